// Round 1
// baseline (207.564 us; speedup 1.0000x reference)
//
#include <hip/hip_runtime.h>

// Problem: single-query attention, N=128 batches, T=2048 timesteps, D=512, fp32.
// context[n,:] = softmax(K[n]·q[n] masked by lens[n]) · V[n]
// Outputs concatenated in d_out: context [128][512] f32, then mask [128][2048] (bool->f32).
// Memory-bound: K+V = 1 GB read once. Roofline ~165 us @ 6.3 TB/s.

#define N_DIM 128
#define T_DIM 2048
#define D_DIM 512
#define NCHUNK 16
#define TCHUNK 128  // T_DIM / NCHUNK
#define NEG_INF_E (-1.0e9f)

// ---------------------------------------------------------------------------
// Phase 1: energy[n][t] = dot(K[n][t], Q[n]) (masked), mask floats to d_out.
// One wave per t. Lane i covers d = {i*4..i*4+3, 256+i*4..256+i*4+3} (2x float4;
// each wave read is a contiguous 1 KB segment -> fully coalesced).
// Grid: 128 n * 16 chunks = 2048 blocks of 256 threads (4 waves, 32 t each).
// ---------------------------------------------------------------------------
__global__ __launch_bounds__(256) void energy_kernel(
    const float* __restrict__ Q, const float* __restrict__ K,
    const int* __restrict__ lens, float* __restrict__ energy,
    float* __restrict__ mask_out) {
  const int n = blockIdx.x >> 4;
  const int chunk = blockIdx.x & 15;
  const int lane = threadIdx.x & 63;
  const int wave = threadIdx.x >> 6;
  const int len = lens[n];

  const float4* Qv = (const float4*)(Q + (size_t)n * D_DIM);
  const float4 q0 = Qv[lane];
  const float4 q1 = Qv[64 + lane];

  for (int tt = wave; tt < TCHUNK; tt += 4) {
    const int t = chunk * TCHUNK + tt;
    const float4* Kv = (const float4*)(K + ((size_t)n * T_DIM + t) * D_DIM);
    const float4 k0 = Kv[lane];
    const float4 k1 = Kv[64 + lane];
    float s = q0.x * k0.x + q0.y * k0.y + q0.z * k0.z + q0.w * k0.w +
              q1.x * k1.x + q1.y * k1.y + q1.z * k1.z + q1.w * k1.w;
#pragma unroll
    for (int off = 32; off; off >>= 1) s += __shfl_xor(s, off, 64);
    if (lane == 0) {
      const bool masked = (t >= len);
      energy[n * T_DIM + t] = masked ? NEG_INF_E : s;
      mask_out[n * T_DIM + t] = masked ? 1.0f : 0.0f;
    }
  }
}

// ---------------------------------------------------------------------------
// Phase 2: in-place masked softmax over each row of energy [128][2048].
// One block (256 threads) per n; each thread owns 8 consecutive energies.
// ---------------------------------------------------------------------------
__global__ __launch_bounds__(256) void softmax_kernel(float* __restrict__ energy) {
  const int n = blockIdx.x;
  const int tid = threadIdx.x;
  float4* row = (float4*)(energy + (size_t)n * T_DIM);
  float4 e0 = row[tid * 2];
  float4 e1 = row[tid * 2 + 1];

  float m = fmaxf(fmaxf(fmaxf(e0.x, e0.y), fmaxf(e0.z, e0.w)),
                  fmaxf(fmaxf(e1.x, e1.y), fmaxf(e1.z, e1.w)));
#pragma unroll
  for (int off = 32; off; off >>= 1) m = fmaxf(m, __shfl_xor(m, off, 64));

  __shared__ float sm[4];
  __shared__ float ss[4];
  if ((tid & 63) == 0) sm[tid >> 6] = m;
  __syncthreads();
  m = fmaxf(fmaxf(sm[0], sm[1]), fmaxf(sm[2], sm[3]));

  float p0 = __expf(e0.x - m), p1 = __expf(e0.y - m);
  float p2 = __expf(e0.z - m), p3 = __expf(e0.w - m);
  float p4 = __expf(e1.x - m), p5 = __expf(e1.y - m);
  float p6 = __expf(e1.z - m), p7 = __expf(e1.w - m);
  float s = ((p0 + p1) + (p2 + p3)) + ((p4 + p5) + (p6 + p7));
#pragma unroll
  for (int off = 32; off; off >>= 1) s += __shfl_xor(s, off, 64);
  if ((tid & 63) == 0) ss[tid >> 6] = s;
  __syncthreads();
  s = (ss[0] + ss[1]) + (ss[2] + ss[3]);

  const float inv = 1.0f / s;
  row[tid * 2] = make_float4(p0 * inv, p1 * inv, p2 * inv, p3 * inv);
  row[tid * 2 + 1] = make_float4(p4 * inv, p5 * inv, p6 * inv, p7 * inv);
}

// ---------------------------------------------------------------------------
// Phase 3: partial context. Block per (n, chunk of 128 t). Each thread owns
// 2 consecutive d (float2); streams 128 V rows (2 KB each, coalesced) with
// attn weights broadcast from LDS. Deterministic partials to ws (no atomics).
// ---------------------------------------------------------------------------
__global__ __launch_bounds__(256) void pv_kernel(
    const float* __restrict__ attn, const float* __restrict__ V,
    float* __restrict__ part) {
  const int n = blockIdx.x >> 4;
  const int chunk = blockIdx.x & 15;
  const int tid = threadIdx.x;

  __shared__ float w[TCHUNK];
  if (tid < TCHUNK) w[tid] = attn[n * T_DIM + chunk * TCHUNK + tid];
  __syncthreads();

  const float2* Vv = (const float2*)(V + ((size_t)n * T_DIM + chunk * TCHUNK) * D_DIM);
  float2 acc = make_float2(0.0f, 0.0f);
#pragma unroll 4
  for (int tt = 0; tt < TCHUNK; ++tt) {
    const float2 v = Vv[(size_t)tt * (D_DIM / 2) + tid];
    const float ww = w[tt];
    acc.x = fmaf(ww, v.x, acc.x);
    acc.y = fmaf(ww, v.y, acc.y);
  }
  float2* P = (float2*)(part + (size_t)(n * NCHUNK + chunk) * D_DIM);
  P[tid] = acc;
}

// ---------------------------------------------------------------------------
// Phase 4: reduce 16 partials -> context [128][512].
// ---------------------------------------------------------------------------
__global__ __launch_bounds__(256) void ctx_reduce_kernel(
    const float* __restrict__ part, float* __restrict__ ctx) {
  const int n = blockIdx.x;
  const int tid = threadIdx.x;
  float2 acc = make_float2(0.0f, 0.0f);
#pragma unroll
  for (int c = 0; c < NCHUNK; ++c) {
    const float2 p = ((const float2*)(part + (size_t)(n * NCHUNK + c) * D_DIM))[tid];
    acc.x += p.x;
    acc.y += p.y;
  }
  ((float2*)(ctx + (size_t)n * D_DIM))[tid] = acc;
}

extern "C" void kernel_launch(void* const* d_in, const int* in_sizes, int n_in,
                              void* d_out, int out_size, void* d_ws, size_t ws_size,
                              hipStream_t stream) {
  const float* Q = (const float*)d_in[0];     // [128][512]
  const float* K = (const float*)d_in[1];     // [128][2048][512]
  const float* V = (const float*)d_in[2];     // [128][2048][512]
  const int* lens = (const int*)d_in[3];      // [128]

  float* out = (float*)d_out;
  float* ctx = out;                           // [128][512]
  float* mask_out = out + N_DIM * D_DIM;      // [128][2048]

  float* energy = (float*)d_ws;               // [128][2048]    (1 MB)
  float* part = energy + N_DIM * T_DIM;       // [128][16][512] (4 MB)

  energy_kernel<<<dim3(N_DIM * NCHUNK), 256, 0, stream>>>(Q, K, lens, energy, mask_out);
  softmax_kernel<<<dim3(N_DIM), 256, 0, stream>>>(energy);
  pv_kernel<<<dim3(N_DIM * NCHUNK), 256, 0, stream>>>(energy, V, part);
  ctx_reduce_kernel<<<dim3(N_DIM), 256, 0, stream>>>(part, ctx);
}

// Round 2
// 135.386 us; speedup vs baseline: 1.5331x; 1.5331x over previous
//
#include <hip/hip_runtime.h>
#include <math.h>

// Single-query attention, N=128, T=2048, D=512, fp32, length-masked.
// Key insight: masked positions (t >= len) have energy -1e9 -> expf underflows
// to exactly 0.0f -> they contribute NOTHING to softmax denom or context.
// So we skip reading K/V there entirely. E[len] ~ T/2 -> ~50% traffic cut.
//
// Kernel 1 (fused, per (n, t-chunk of 128)): energy chunk (K read), local
// softmax (m_c, s_c), unnormalized PV partial (V read) -> ws. Writes mask.
// Kernel 2: combine chunks with exp(m_c - M)/S scaling -> context.

#define N_DIM 128
#define T_DIM 2048
#define D_DIM 512
#define NCHUNK 16
#define TCHUNK 128  // T_DIM / NCHUNK

__global__ __launch_bounds__(256) void fused_attn_kernel(
    const float* __restrict__ Q, const float* __restrict__ K,
    const float* __restrict__ V, const int* __restrict__ lens,
    float* __restrict__ mask_out, float* __restrict__ part,
    float* __restrict__ ms) {
  const int n = blockIdx.x >> 4;
  const int c = blockIdx.x & 15;
  const int tid = threadIdx.x;
  const int lane = tid & 63;
  const int wave = tid >> 6;
  const int len = lens[n];
  const int t0 = c * TCHUNK;

  // Mask output for this chunk: 128 floats, float4 x 32 threads, coalesced.
  if (tid < TCHUNK / 4) {
    const int tb = t0 + tid * 4;
    float4 mv;
    mv.x = (tb + 0 >= len) ? 1.0f : 0.0f;
    mv.y = (tb + 1 >= len) ? 1.0f : 0.0f;
    mv.z = (tb + 2 >= len) ? 1.0f : 0.0f;
    mv.w = (tb + 3 >= len) ? 1.0f : 0.0f;
    ((float4*)(mask_out + (size_t)n * T_DIM + t0))[tid] = mv;
  }
  if (t0 >= len) return;  // fully masked chunk: no K/V reads, no partials
  const int nvalid = min(TCHUNK, len - t0);

  __shared__ float e[TCHUNK];   // energies, then attention weights (unnorm)
  __shared__ float red_m[4];
  __shared__ float red_s[4];

  const float4* Qv = (const float4*)(Q + (size_t)n * D_DIM);
  const float4 q0 = Qv[lane];
  const float4 q1 = Qv[64 + lane];

  // ---- Energy phase: one wave per t, lane i covers d = 4i..4i+3, 256+4i..4i+3.
  for (int tt = wave; tt < nvalid; tt += 4) {
    const float4* Kv = (const float4*)(K + ((size_t)n * T_DIM + t0 + tt) * D_DIM);
    const float4 k0 = Kv[lane];
    const float4 k1 = Kv[64 + lane];
    float s = q0.x * k0.x + q0.y * k0.y + q0.z * k0.z + q0.w * k0.w +
              q1.x * k1.x + q1.y * k1.y + q1.z * k1.z + q1.w * k1.w;
#pragma unroll
    for (int off = 32; off; off >>= 1) s += __shfl_xor(s, off, 64);
    if (lane == 0) e[tt] = s;
  }
  __syncthreads();

  // ---- Local max over e[0..nvalid)
  float m = (tid < nvalid) ? e[tid] : -INFINITY;
#pragma unroll
  for (int off = 32; off; off >>= 1) m = fmaxf(m, __shfl_xor(m, off, 64));
  if (lane == 0) red_m[wave] = m;
  __syncthreads();
  m = fmaxf(fmaxf(red_m[0], red_m[1]), fmaxf(red_m[2], red_m[3]));

  // ---- p = exp(e - m), local sum; store p back to LDS (zeros past nvalid).
  float p = 0.0f;
  if (tid < nvalid) p = __expf(e[tid] - m);
  if (tid < TCHUNK) e[tid] = p;
  float s = p;
#pragma unroll
  for (int off = 32; off; off >>= 1) s += __shfl_xor(s, off, 64);
  if (lane == 0) red_s[wave] = s;
  __syncthreads();  // red_s visible AND e[]=p writes visible
  s = (red_s[0] + red_s[1]) + (red_s[2] + red_s[3]);
  if (tid == 0) {
    ms[(n * NCHUNK + c) * 2 + 0] = m;
    ms[(n * NCHUNK + c) * 2 + 1] = s;
  }

  // ---- PV phase: thread owns float2 of D; stream nvalid V rows (2KB each).
  float2 acc = make_float2(0.0f, 0.0f);
  const float2* Vv = (const float2*)(V + ((size_t)n * T_DIM + t0) * D_DIM);
#pragma unroll 4
  for (int tt = 0; tt < nvalid; ++tt) {
    const float2 v = Vv[(size_t)tt * (D_DIM / 2) + tid];
    const float w = e[tt];
    acc.x = fmaf(w, v.x, acc.x);
    acc.y = fmaf(w, v.y, acc.y);
  }
  ((float2*)(part + (size_t)(n * NCHUNK + c) * D_DIM))[tid] = acc;
}

// Combine per-chunk partials: M = max m_c, S = sum s_c*exp(m_c-M),
// ctx = sum_c part_c * exp(m_c-M) / S. Skips chunks beyond len.
__global__ __launch_bounds__(256) void ctx_combine_kernel(
    const float* __restrict__ part, const float* __restrict__ ms,
    const int* __restrict__ lens, float* __restrict__ ctx) {
  const int n = blockIdx.x;
  const int tid = threadIdx.x;
  const int len = lens[n];
  const int nc = (len + TCHUNK - 1) / TCHUNK;  // >= 1 since len >= 1

  float M = -INFINITY;
  for (int c = 0; c < nc; ++c) M = fmaxf(M, ms[(n * NCHUNK + c) * 2]);
  float S = 0.0f;
  for (int c = 0; c < nc; ++c)
    S += ms[(n * NCHUNK + c) * 2 + 1] * __expf(ms[(n * NCHUNK + c) * 2] - M);
  const float invS = 1.0f / S;

  float2 acc = make_float2(0.0f, 0.0f);
  for (int c = 0; c < nc; ++c) {
    const float sc = __expf(ms[(n * NCHUNK + c) * 2] - M) * invS;
    const float2 p = ((const float2*)(part + (size_t)(n * NCHUNK + c) * D_DIM))[tid];
    acc.x = fmaf(sc, p.x, acc.x);
    acc.y = fmaf(sc, p.y, acc.y);
  }
  ((float2*)(ctx + (size_t)n * D_DIM))[tid] = acc;
}

extern "C" void kernel_launch(void* const* d_in, const int* in_sizes, int n_in,
                              void* d_out, int out_size, void* d_ws, size_t ws_size,
                              hipStream_t stream) {
  const float* Q = (const float*)d_in[0];     // [128][512]
  const float* K = (const float*)d_in[1];     // [128][2048][512]
  const float* V = (const float*)d_in[2];     // [128][2048][512]
  const int* lens = (const int*)d_in[3];      // [128]

  float* out = (float*)d_out;
  float* ctx = out;                           // [128][512]
  float* mask_out = out + N_DIM * D_DIM;      // [128][2048]

  float* part = (float*)d_ws;                 // [128][16][512] (4 MB)
  float* ms = part + N_DIM * NCHUNK * D_DIM;  // [128][16][2]   (16 KB)

  fused_attn_kernel<<<dim3(N_DIM * NCHUNK), 256, 0, stream>>>(
      Q, K, V, lens, mask_out, part, ms);
  ctx_combine_kernel<<<dim3(N_DIM), 256, 0, stream>>>(part, ms, lens, ctx);
}